// Round 1
// baseline (876.664 us; speedup 1.0000x reference)
//
#include <hip/hip_runtime.h>
#include <hip/hip_bf16.h>

// Problem constants (fixed by reference)
#define Nn 16000
#define Ee 256000
#define Tt 5
#define HIDd 64
#define LHh 128
#define GATES 512  // 4*LH

// Workspace layout (float offsets)
#define OFF_DINV 0
#define OFF_AGG   (OFF_DINV + Nn)            // T*N
#define OFF_H0    (OFF_AGG + Tt*Nn)          // N*128
#define OFF_C0    (OFF_H0 + Nn*LHh)
#define OFF_H1    (OFF_C0 + Nn*LHh)
#define OFF_C1    (OFF_H1 + Nn*LHh)
#define OFF_W0T   (OFF_C1 + Nn*LHh)          // 192*512
#define OFF_W1T   (OFF_W0T + 192*GATES)      // 256*512
#define OFF_B0    (OFF_W1T + 256*GATES)      // 512
#define OFF_B1    (OFF_B0 + GATES)           // 512
#define OFF_DEG   (OFF_B1 + GATES)           // N ints

__device__ __forceinline__ float fsig(float x) { return 1.f / (1.f + __expf(-x)); }
__device__ __forceinline__ float ftanh(float x) { return 1.f - 2.f / (1.f + __expf(2.f * x)); }

// ---- prep: transpose/concat weights, fold biases, zero degree array ----
__global__ void prep_weights(const float* __restrict__ w_ih0, const float* __restrict__ w_hh0,
                             const float* __restrict__ b_ih0, const float* __restrict__ b_hh0,
                             const float* __restrict__ w_ih1, const float* __restrict__ w_hh1,
                             const float* __restrict__ b_ih1, const float* __restrict__ b_hh1,
                             float* __restrict__ W0T, float* __restrict__ W1T,
                             float* __restrict__ B0, float* __restrict__ B1,
                             int* __restrict__ deg) {
    const int A = 192 * GATES;
    const int B = 256 * GATES;
    int idx = blockIdx.x * blockDim.x + threadIdx.x;
    if (idx < A) {
        int k = idx >> 9, q = idx & 511;
        W0T[idx] = (k < 64) ? w_ih0[q * 64 + k] : w_hh0[q * 128 + (k - 64)];
    } else if (idx < A + B) {
        int i2 = idx - A;
        int k = i2 >> 9, q = i2 & 511;
        W1T[i2] = (k < 128) ? w_ih1[q * 128 + k] : w_hh1[q * 128 + (k - 128)];
    } else if (idx < A + B + GATES) {
        int q = idx - A - B;
        B0[q] = b_ih0[q] + b_hh0[q];
    } else if (idx < A + B + 2 * GATES) {
        int q = idx - A - B - GATES;
        B1[q] = b_ih1[q] + b_hh1[q];
    } else if (idx < A + B + 2 * GATES + Nn) {
        deg[idx - A - B - 2 * GATES] = 0;
    }
}

// ---- degree count over dst row ----
__global__ void deg_count(const int* __restrict__ ei, int* __restrict__ deg) {
    int e = blockIdx.x * blockDim.x + threadIdx.x;
    if (e < Ee) atomicAdd(&deg[ei[Ee + e]], 1);
}

// ---- dinv + self-loop init of agg ----
__global__ void agg_init(const float* __restrict__ x, const int* __restrict__ deg,
                         float* __restrict__ dinv, float* __restrict__ agg) {
    int n = blockIdx.x * blockDim.x + threadIdx.x;
    if (n >= Nn) return;
    float di = rsqrtf((float)(deg[n] + 1));  // +1 self loop; always > 0
    dinv[n] = di;
    float dd = di * di;
    #pragma unroll
    for (int t = 0; t < Tt; ++t) agg[t * Nn + n] = x[n * Tt + t] * dd;
}

// ---- edge scatter: agg[t][d] += x[s,t]*dinv[s]*dinv[d] ----
__global__ void edge_scatter(const float* __restrict__ x, const int* __restrict__ ei,
                             const float* __restrict__ dinv, float* __restrict__ agg) {
    int e = blockIdx.x * blockDim.x + threadIdx.x;
    if (e >= Ee) return;
    int s = ei[e], d = ei[Ee + e];
    float cf = dinv[s] * dinv[d];
    #pragma unroll
    for (int t = 0; t < Tt; ++t) atomicAdd(&agg[t * Nn + d], x[s * Tt + t] * cf);
}

// ---- fused LSTM step: gates GEMM + cell update, 32 nodes/block ----
// K_IN=64 (layer0, input generated from agg via gcn_w/gcn_b) or 128 (layer1, input = h0).
template <int K_IN, bool FIRST>
__global__ __launch_bounds__(256) void lstm_step(
    const float* __restrict__ xin,     // layer0: agg slice (N floats); layer1: h0 (N x 128)
    const float* __restrict__ gw, const float* __restrict__ gb,   // gcn params (layer0 only)
    const float* __restrict__ WT,      // (K_IN+128) x 512 transposed weights
    const float* __restrict__ bias,    // 512 folded biases
    float* __restrict__ h, float* __restrict__ c) {
    constexpr int KT = K_IN + 128;
    constexpr int S = 36;              // LDS row stride (pad: keeps float4 reads 16B-aligned)
    __shared__ float X[KT * S];
    const int tid = threadIdx.x;
    const int n0 = blockIdx.x * 32;

    // --- stage input rows 0..K_IN-1 ---
    if (K_IN == 64) {
        for (int idx = tid; idx < 64 * 32; idx += 256) {
            int j = idx >> 5, n = idx & 31;
            float a = xin[n0 + n];
            X[j * S + n] = fmaxf(gw[j] * a + gb[j], 0.f);
        }
    } else {
        #pragma unroll
        for (int r = 0; r < 4; ++r) {
            int q = tid + 256 * r;          // float4 index over 32x128 tile
            int n = q >> 5;
            int kk = (q & 31) * 4;
            float4 v = ((const float4*)(xin + (size_t)(n0 + n) * 128))[q & 31];
            X[(kk + 0) * S + n] = v.x; X[(kk + 1) * S + n] = v.y;
            X[(kk + 2) * S + n] = v.z; X[(kk + 3) * S + n] = v.w;
        }
    }
    // --- stage recurrent rows K_IN..KT-1 ---
    if (FIRST) {
        for (int idx = tid; idx < 128 * 32; idx += 256) {
            int k = idx >> 5, n = idx & 31;
            X[(K_IN + k) * S + n] = 0.f;
        }
    } else {
        #pragma unroll
        for (int r = 0; r < 4; ++r) {
            int q = tid + 256 * r;
            int n = q >> 5;
            int kk = (q & 31) * 4;
            float4 v = ((const float4*)(h + (size_t)(n0 + n) * 128))[q & 31];
            X[(K_IN + kk + 0) * S + n] = v.x; X[(K_IN + kk + 1) * S + n] = v.y;
            X[(K_IN + kk + 2) * S + n] = v.z; X[(K_IN + kk + 3) * S + n] = v.w;
        }
    }
    __syncthreads();

    const int u = tid & 127;           // hidden unit
    const int hf = tid >> 7;           // node half
    const int nb = hf * 16;
    float acc0[16], acc1[16], acc2[16], acc3[16];
    #pragma unroll
    for (int j = 0; j < 16; ++j) { acc0[j] = acc1[j] = acc2[j] = acc3[j] = 0.f; }

    const float* wp = WT + u;
    #pragma unroll 2
    for (int k = 0; k < KT; ++k) {
        const float* xr = &X[k * S + nb];
        float4 a = *(const float4*)(xr);
        float4 b = *(const float4*)(xr + 4);
        float4 cc = *(const float4*)(xr + 8);
        float4 d = *(const float4*)(xr + 12);
        const float* w = wp + k * GATES;
        float wi = w[0], wf = w[128], wg = w[256], wo = w[384];
        float xv[16];
        xv[0] = a.x;  xv[1] = a.y;  xv[2] = a.z;  xv[3] = a.w;
        xv[4] = b.x;  xv[5] = b.y;  xv[6] = b.z;  xv[7] = b.w;
        xv[8] = cc.x; xv[9] = cc.y; xv[10] = cc.z; xv[11] = cc.w;
        xv[12] = d.x; xv[13] = d.y; xv[14] = d.z; xv[15] = d.w;
        #pragma unroll
        for (int j = 0; j < 16; ++j) {
            acc0[j] = fmaf(wi, xv[j], acc0[j]);
            acc1[j] = fmaf(wf, xv[j], acc1[j]);
            acc2[j] = fmaf(wg, xv[j], acc2[j]);
            acc3[j] = fmaf(wo, xv[j], acc3[j]);
        }
    }

    const float bi = bias[u], bf = bias[128 + u], bg = bias[256 + u], bo = bias[384 + u];
    #pragma unroll
    for (int j = 0; j < 16; ++j) {
        int node = n0 + nb + j;
        size_t off = (size_t)node * 128 + u;
        float co = FIRST ? 0.f : c[off];
        float i_ = fsig(acc0[j] + bi);
        float f_ = fsig(acc1[j] + bf);
        float g_ = ftanh(acc2[j] + bg);
        float o_ = fsig(acc3[j] + bo);
        float cn = f_ * co + i_ * g_;
        float hn = o_ * ftanh(cn);
        c[off] = cn;
        h[off] = hn;
    }
}

// ---- head: out[n] = x[n,T-1] + relu(h1[n]@pw1.T+pb1)@pw2.T + pb2 ----
// one wave (64 lanes = 64 pw1 rows) per node
__global__ __launch_bounds__(256) void head_kernel(const float* __restrict__ x,
                                                   const float* __restrict__ h1,
                                                   const float* __restrict__ pw1,
                                                   const float* __restrict__ pb1,
                                                   const float* __restrict__ pw2,
                                                   const float* __restrict__ pb2,
                                                   float* __restrict__ out) {
    int lane = threadIdx.x & 63;
    int node = blockIdx.x * 4 + (threadIdx.x >> 6);
    const float4* hp = (const float4*)(h1 + (size_t)node * 128);
    const float4* wp = (const float4*)(pw1 + (size_t)lane * 128);
    float s = pb1[lane];
    #pragma unroll
    for (int k4 = 0; k4 < 32; ++k4) {
        float4 hv = hp[k4];
        float4 wv = wp[k4];
        s = fmaf(hv.x, wv.x, s); s = fmaf(hv.y, wv.y, s);
        s = fmaf(hv.z, wv.z, s); s = fmaf(hv.w, wv.w, s);
    }
    float y = fmaxf(s, 0.f) * pw2[lane];
    #pragma unroll
    for (int off = 32; off >= 1; off >>= 1) y += __shfl_down(y, off);
    if (lane == 0) out[node] = x[node * Tt + (Tt - 1)] + y + pb2[0];
}

extern "C" void kernel_launch(void* const* d_in, const int* in_sizes, int n_in,
                              void* d_out, int out_size, void* d_ws, size_t ws_size,
                              hipStream_t stream) {
    const float* x      = (const float*)d_in[0];
    const int*   ei     = (const int*)d_in[1];
    const float* gcn_w  = (const float*)d_in[2];
    const float* gcn_b  = (const float*)d_in[3];
    const float* w_ih0  = (const float*)d_in[4];
    const float* w_hh0  = (const float*)d_in[5];
    const float* b_ih0  = (const float*)d_in[6];
    const float* b_hh0  = (const float*)d_in[7];
    const float* w_ih1  = (const float*)d_in[8];
    const float* w_hh1  = (const float*)d_in[9];
    const float* b_ih1  = (const float*)d_in[10];
    const float* b_hh1  = (const float*)d_in[11];
    const float* pw1    = (const float*)d_in[12];
    const float* pb1    = (const float*)d_in[13];
    const float* pw2    = (const float*)d_in[14];
    const float* pb2    = (const float*)d_in[15];
    float* out = (float*)d_out;

    float* wsf  = (float*)d_ws;
    float* dinv = wsf + OFF_DINV;
    float* agg  = wsf + OFF_AGG;
    float* h0   = wsf + OFF_H0;
    float* c0   = wsf + OFF_C0;
    float* h1   = wsf + OFF_H1;
    float* c1   = wsf + OFF_C1;
    float* W0T  = wsf + OFF_W0T;
    float* W1T  = wsf + OFF_W1T;
    float* B0   = wsf + OFF_B0;
    float* B1   = wsf + OFF_B1;
    int*   deg  = (int*)(wsf + OFF_DEG);

    // 1) prep weights + zero degree
    {
        int total = 192 * GATES + 256 * GATES + 2 * GATES + Nn;
        prep_weights<<<(total + 255) / 256, 256, 0, stream>>>(
            w_ih0, w_hh0, b_ih0, b_hh0, w_ih1, w_hh1, b_ih1, b_hh1,
            W0T, W1T, B0, B1, deg);
    }
    // 2) degree
    deg_count<<<(Ee + 255) / 256, 256, 0, stream>>>(ei, deg);
    // 3) dinv + self-loop agg init
    agg_init<<<(Nn + 255) / 256, 256, 0, stream>>>(x, deg, dinv, agg);
    // 4) edge scatter
    edge_scatter<<<(Ee + 255) / 256, 256, 0, stream>>>(x, ei, dinv, agg);

    // 5) LSTM steps (layer0 then layer1 each t)
    const int blocks = Nn / 32;  // 500
    lstm_step<64, true ><<<blocks, 256, 0, stream>>>(agg + 0 * Nn, gcn_w, gcn_b, W0T, B0, h0, c0);
    lstm_step<128, true><<<blocks, 256, 0, stream>>>(h0, nullptr, nullptr, W1T, B1, h1, c1);
    for (int t = 1; t < Tt; ++t) {
        lstm_step<64, false ><<<blocks, 256, 0, stream>>>(agg + t * Nn, gcn_w, gcn_b, W0T, B0, h0, c0);
        lstm_step<128, false><<<blocks, 256, 0, stream>>>(h0, nullptr, nullptr, W1T, B1, h1, c1);
    }

    // 6) head
    head_kernel<<<Nn / 4, 256, 0, stream>>>(x, h1, pw1, pb1, pw2, pb2, out);
}

// Round 3
// 552.395 us; speedup vs baseline: 1.5870x; 1.5870x over previous
//
#include <hip/hip_runtime.h>
#include <hip/hip_bf16.h>

// Problem constants (fixed by reference)
#define Nn 16000
#define Ee 256000
#define Tt 5
#define HIDd 64
#define LHh 128
#define GATES 512  // 4*LH

typedef _Float16 f16;
typedef __attribute__((ext_vector_type(8))) _Float16 f16x8;
typedef __attribute__((ext_vector_type(4))) float f32x4;

// ---- workspace layout (float units) ----
#define OFF_DINV 0
#define OFF_AGG   (OFF_DINV + Nn)              // N*5 fp32, node-major [n][t]
#define OFF_C0    (OFF_AGG + Nn*Tt)            // N*128 fp32
#define OFF_C1    (OFF_C0 + Nn*LHh)            // N*128 fp32
#define OFF_B0    (OFF_C1 + Nn*LHh)            // 512
#define OFF_B1    (OFF_B0 + GATES)             // 512
#define OFF_DEG   (OFF_B1 + GATES)             // N ints
#define OFF_H0A   (OFF_DEG + Nn)               // N*128 f16 = N*64 float units
#define OFF_H0B   (OFF_H0A + Nn*64)
#define OFF_H1A   (OFF_H0B + Nn*64)
#define OFF_H1B   (OFF_H1A + Nn*64)
#define OFF_W0T   (OFF_H1B + Nn*64)            // 512*192 f16 = 49152 floats
#define OFF_W1T   (OFF_W0T + 512*192/2)        // 512*256 f16 = 65536 floats
#define OFF_END   (OFF_W1T + 512*256/2)

__device__ __forceinline__ float fsig(float x) { return 1.f / (1.f + __expf(-x)); }
__device__ __forceinline__ float ftanh(float x) { return 1.f - 2.f / (1.f + __expf(2.f * x)); }

// ---- prep: transpose weights to f16 [q][k], fold biases, zero degree ----
// grid: [0,512) W0T rows | [512,1024) W1T rows | [1024,1028) biases | [1028,1091) deg zero
__global__ void prep_weights(const float* __restrict__ w_ih0, const float* __restrict__ w_hh0,
                             const float* __restrict__ b_ih0, const float* __restrict__ b_hh0,
                             const float* __restrict__ w_ih1, const float* __restrict__ w_hh1,
                             const float* __restrict__ b_ih1, const float* __restrict__ b_hh1,
                             f16* __restrict__ W0T, f16* __restrict__ W1T,
                             float* __restrict__ B0, float* __restrict__ B1,
                             int* __restrict__ deg) {
    int b = blockIdx.x, t = threadIdx.x;
    if (b < 512) {
        if (t < 192) {
            float v = (t < 64) ? w_ih0[b * 64 + t] : w_hh0[b * 128 + (t - 64)];
            W0T[b * 192 + t] = (f16)v;
        }
    } else if (b < 1024) {
        int q = b - 512;
        float v = (t < 128) ? w_ih1[q * 128 + t] : w_hh1[q * 128 + (t - 128)];
        W1T[q * 256 + t] = (f16)v;
    } else if (b < 1028) {
        int idx = (b - 1024) * 256 + t;
        if (idx < 512) B0[idx] = b_ih0[idx] + b_hh0[idx];
        else           B1[idx - 512] = b_ih1[idx - 512] + b_hh1[idx - 512];
    } else {
        int n = (b - 1028) * 256 + t;
        if (n < Nn) deg[n] = 0;
    }
}

// ---- degree count over dst row ----
__global__ void deg_count(const int* __restrict__ ei, int* __restrict__ deg) {
    int e = blockIdx.x * blockDim.x + threadIdx.x;
    if (e < Ee) atomicAdd(&deg[ei[Ee + e]], 1);
}

// ---- dinv + self-loop init of agg (node-major [n][t]) ----
__global__ void agg_init(const float* __restrict__ x, const int* __restrict__ deg,
                         float* __restrict__ dinv, float* __restrict__ agg) {
    int n = blockIdx.x * blockDim.x + threadIdx.x;
    if (n >= Nn) return;
    float di = rsqrtf((float)(deg[n] + 1));  // +1 self loop; always > 0
    dinv[n] = di;
    float dd = di * di;
    #pragma unroll
    for (int t = 0; t < Tt; ++t) agg[n * Tt + t] = x[n * Tt + t] * dd;
}

// ---- edge scatter: agg[d][t] += x[s,t]*dinv[s]*dinv[d] ----
__global__ void edge_scatter(const float* __restrict__ x, const int* __restrict__ ei,
                             const float* __restrict__ dinv, float* __restrict__ agg) {
    int e = blockIdx.x * blockDim.x + threadIdx.x;
    if (e >= Ee) return;
    int s = ei[e], d = ei[Ee + e];
    float cf = dinv[s] * dinv[d];
    #pragma unroll
    for (int t = 0; t < Tt; ++t) atomicAdd(&agg[d * Tt + t], x[s * Tt + t] * cf);
}

// ---- fused LSTM step, MFMA f16 ----
// Block: 256 thr = 4 waves; wave = 16 nodes x 16 u x 4 gates (4 C-frags).
// Block tile: 32 nodes (blockIdx.x) x 32 u (blockIdx.y).
// X staged in LDS as f16 [node][k], row stride KT+8 (2-way bank aliasing = free).
// B-fragments read from global W[q][k] f16 (L2-resident, 16B/lane contiguous).
template <int K_IN, bool FIRST>
__global__ __launch_bounds__(256, 6) void lstm_mfma(
    const float* __restrict__ agg, int tcol,      // layer0 input source
    const f16* __restrict__ xin16,                // layer1 input (h0 current)
    const f16* __restrict__ hrec,                 // recurrent h (prev step), unused if FIRST
    const float* __restrict__ gw, const float* __restrict__ gb,  // gcn params (layer0)
    const f16* __restrict__ WT,                   // [512][KT] f16
    const float* __restrict__ bias,               // 512 folded biases
    f16* __restrict__ hout, float* __restrict__ c) {
    constexpr int KT = K_IN + 128;
    constexpr int S = KT + 8;                     // f16 row stride: 2-way bank aliasing only
    __shared__ f16 X[32 * S];
    const int tid = threadIdx.x;
    const int n0 = blockIdx.x * 32;
    const int ub = blockIdx.y * 32;

    // --- stage input cols 0..K_IN-1 ---
    if constexpr (K_IN == 64) {
        // generated GCN features: relu(gw[j]*agg[n][t] + gb[j]); 8 threads/node, 8 f16 each
        int node = tid >> 3, j0 = (tid & 7) * 8;
        float a = agg[(size_t)(n0 + node) * Tt + tcol];
        f16x8 v;
        #pragma unroll
        for (int j = 0; j < 8; ++j)
            v[j] = (f16)fmaxf(gw[j0 + j] * a + gb[j0 + j], 0.f);
        *(f16x8*)&X[node * S + j0] = v;
    } else {
        // h0 current, f16 [n][128]
        #pragma unroll
        for (int r = 0; r < 2; ++r) {
            int chunk = tid + 256 * r;
            int node = chunk >> 4, j0 = (chunk & 15) * 8;
            f16x8 v = *(const f16x8*)(xin16 + (size_t)(n0 + node) * 128 + j0);
            *(f16x8*)&X[node * S + j0] = v;
        }
    }
    // --- stage recurrent cols K_IN..K_IN+127 ---
    #pragma unroll
    for (int r = 0; r < 2; ++r) {
        int chunk = tid + 256 * r;
        int node = chunk >> 4, j0 = (chunk & 15) * 8;
        f16x8 v;
        if constexpr (FIRST) {
            #pragma unroll
            for (int j = 0; j < 8; ++j) v[j] = (f16)0.f;
        } else {
            v = *(const f16x8*)(hrec + (size_t)(n0 + node) * 128 + j0);
        }
        *(f16x8*)&X[node * S + K_IN + j0] = v;
    }
    __syncthreads();

    const int lane = tid & 63;
    const int wave = tid >> 6;
    const int l = lane & 15;           // A row / C col
    const int quad = lane >> 4;        // k-group / C row-group
    const int wn = wave & 1;           // node half (16)
    const int wu = wave >> 1;          // u half (16)
    const int ucol = ub + wu * 16 + l; // hidden unit 0..127

    const f16* ap = &X[(wn * 16 + l) * S + quad * 8];
    const f16* bp0 = WT + (size_t)(0 * 128 + ucol) * KT + quad * 8;
    const f16* bp1 = WT + (size_t)(1 * 128 + ucol) * KT + quad * 8;
    const f16* bp2 = WT + (size_t)(2 * 128 + ucol) * KT + quad * 8;
    const f16* bp3 = WT + (size_t)(3 * 128 + ucol) * KT + quad * 8;

    f32x4 acc0 = {0.f, 0.f, 0.f, 0.f}, acc1 = acc0, acc2 = acc0, acc3 = acc0;
    #pragma unroll
    for (int kt = 0; kt < KT / 32; ++kt) {
        f16x8 a = *(const f16x8*)(ap + kt * 32);
        f16x8 b0 = *(const f16x8*)(bp0 + kt * 32);
        f16x8 b1 = *(const f16x8*)(bp1 + kt * 32);
        f16x8 b2 = *(const f16x8*)(bp2 + kt * 32);
        f16x8 b3 = *(const f16x8*)(bp3 + kt * 32);
        acc0 = __builtin_amdgcn_mfma_f32_16x16x32_f16(a, b0, acc0, 0, 0, 0);
        acc1 = __builtin_amdgcn_mfma_f32_16x16x32_f16(a, b1, acc1, 0, 0, 0);
        acc2 = __builtin_amdgcn_mfma_f32_16x16x32_f16(a, b2, acc2, 0, 0, 0);
        acc3 = __builtin_amdgcn_mfma_f32_16x16x32_f16(a, b3, acc3, 0, 0, 0);
    }

    const float bi = bias[ucol], bf = bias[128 + ucol];
    const float bg = bias[256 + ucol], bo = bias[384 + ucol];
    #pragma unroll
    for (int r = 0; r < 4; ++r) {
        int node = n0 + wn * 16 + quad * 4 + r;   // C row = quad*4 + reg
        size_t off = (size_t)node * 128 + ucol;
        float co = FIRST ? 0.f : c[off];
        float i_ = fsig(acc0[r] + bi);
        float f_ = fsig(acc1[r] + bf);
        float g_ = ftanh(acc2[r] + bg);
        float o_ = fsig(acc3[r] + bo);
        float cn = f_ * co + i_ * g_;
        float hn = o_ * ftanh(cn);
        c[off] = cn;
        hout[off] = (f16)hn;
    }
}

// ---- head: out[n] = x[n,T-1] + relu(h1[n]@pw1.T+pb1)@pw2.T + pb2 ----
__global__ __launch_bounds__(256) void head_kernel(const float* __restrict__ x,
                                                   const f16* __restrict__ h1,
                                                   const float* __restrict__ pw1,
                                                   const float* __restrict__ pb1,
                                                   const float* __restrict__ pw2,
                                                   const float* __restrict__ pb2,
                                                   float* __restrict__ out) {
    int lane = threadIdx.x & 63;
    int node = blockIdx.x * 4 + (threadIdx.x >> 6);
    const f16x8* hp = (const f16x8*)(h1 + (size_t)node * 128);
    const float4* wp = (const float4*)(pw1 + (size_t)lane * 128);
    float s = pb1[lane];
    #pragma unroll
    for (int k8 = 0; k8 < 16; ++k8) {
        f16x8 hv = hp[k8];
        float4 w0 = wp[k8 * 2], w1 = wp[k8 * 2 + 1];
        s = fmaf((float)hv[0], w0.x, s); s = fmaf((float)hv[1], w0.y, s);
        s = fmaf((float)hv[2], w0.z, s); s = fmaf((float)hv[3], w0.w, s);
        s = fmaf((float)hv[4], w1.x, s); s = fmaf((float)hv[5], w1.y, s);
        s = fmaf((float)hv[6], w1.z, s); s = fmaf((float)hv[7], w1.w, s);
    }
    float y = fmaxf(s, 0.f) * pw2[lane];
    #pragma unroll
    for (int off = 32; off >= 1; off >>= 1) y += __shfl_down(y, off);
    if (lane == 0) out[node] = x[node * Tt + (Tt - 1)] + y + pb2[0];
}

extern "C" void kernel_launch(void* const* d_in, const int* in_sizes, int n_in,
                              void* d_out, int out_size, void* d_ws, size_t ws_size,
                              hipStream_t stream) {
    const float* x      = (const float*)d_in[0];
    const int*   ei     = (const int*)d_in[1];
    const float* gcn_w  = (const float*)d_in[2];
    const float* gcn_b  = (const float*)d_in[3];
    const float* w_ih0  = (const float*)d_in[4];
    const float* w_hh0  = (const float*)d_in[5];
    const float* b_ih0  = (const float*)d_in[6];
    const float* b_hh0  = (const float*)d_in[7];
    const float* w_ih1  = (const float*)d_in[8];
    const float* w_hh1  = (const float*)d_in[9];
    const float* b_ih1  = (const float*)d_in[10];
    const float* b_hh1  = (const float*)d_in[11];
    const float* pw1    = (const float*)d_in[12];
    const float* pb1    = (const float*)d_in[13];
    const float* pw2    = (const float*)d_in[14];
    const float* pb2    = (const float*)d_in[15];
    float* out = (float*)d_out;

    float* wsf  = (float*)d_ws;
    float* dinv = wsf + OFF_DINV;
    float* agg  = wsf + OFF_AGG;
    float* c0   = wsf + OFF_C0;
    float* c1   = wsf + OFF_C1;
    float* B0   = wsf + OFF_B0;
    float* B1   = wsf + OFF_B1;
    int*   deg  = (int*)(wsf + OFF_DEG);
    f16*   h0b[2] = { (f16*)(wsf + OFF_H0A), (f16*)(wsf + OFF_H0B) };
    f16*   h1b[2] = { (f16*)(wsf + OFF_H1A), (f16*)(wsf + OFF_H1B) };
    f16*   W0T  = (f16*)(wsf + OFF_W0T);
    f16*   W1T  = (f16*)(wsf + OFF_W1T);

    // 1) prep weights (f16 transpose) + fold biases + zero degree
    prep_weights<<<1091, 256, 0, stream>>>(w_ih0, w_hh0, b_ih0, b_hh0,
                                           w_ih1, w_hh1, b_ih1, b_hh1,
                                           W0T, W1T, B0, B1, deg);
    // 2) degree
    deg_count<<<(Ee + 255) / 256, 256, 0, stream>>>(ei, deg);
    // 3) dinv + self-loop agg init
    agg_init<<<(Nn + 255) / 256, 256, 0, stream>>>(x, deg, dinv, agg);
    // 4) edge scatter
    edge_scatter<<<(Ee + 255) / 256, 256, 0, stream>>>(x, ei, dinv, agg);

    // 5) LSTM: layer0 then layer1 per step; h double-buffered (u-split blocks
    //    read other blocks' h at staging -> in-place would race)
    dim3 grid(Nn / 32, 4);
    lstm_mfma<64, true ><<<grid, 256, 0, stream>>>(agg, 0, nullptr, nullptr,
                                                   gcn_w, gcn_b, W0T, B0, h0b[0], c0);
    lstm_mfma<128, true><<<grid, 256, 0, stream>>>(nullptr, 0, h0b[0], nullptr,
                                                   nullptr, nullptr, W1T, B1, h1b[0], c1);
    for (int t = 1; t < Tt; ++t) {
        lstm_mfma<64, false ><<<grid, 256, 0, stream>>>(agg, t, nullptr, h0b[(t - 1) & 1],
                                                        gcn_w, gcn_b, W0T, B0, h0b[t & 1], c0);
        lstm_mfma<128, false><<<grid, 256, 0, stream>>>(nullptr, 0, h0b[t & 1], h1b[(t - 1) & 1],
                                                        nullptr, nullptr, W1T, B1, h1b[t & 1], c1);
    }

    // 6) head (reads h1 of t=4 -> buffer index 0)
    head_kernel<<<Nn / 4, 256, 0, stream>>>(x, h1b[0], pw1, pb1, pw2, pb2, out);
}

// Round 4
// 550.717 us; speedup vs baseline: 1.5919x; 1.0030x over previous
//
#include <hip/hip_runtime.h>
#include <hip/hip_bf16.h>

// Problem constants (fixed by reference)
#define Nn 16000
#define Ee 256000
#define Tt 5
#define HIDd 64
#define LHh 128
#define GATES 512  // 4*LH
#define NREP 16    // atomic-contention replicas

typedef _Float16 f16;
typedef __attribute__((ext_vector_type(8))) _Float16 f16x8;
typedef __attribute__((ext_vector_type(4))) float f32x4;

// ---- workspace layout (float units) ----
#define OFF_DINV 0
#define OFF_AGG   (OFF_DINV + Nn)              // N*5 fp32 final, node-major [n][t]
#define OFF_C0    (OFF_AGG + Nn*Tt)            // N*128 fp32  (aliased: agg replicas, NREP*N*5)
#define OFF_C1    (OFF_C0 + Nn*LHh)            // N*128 fp32  (aliased: deg replicas, NREP*N ints)
#define OFF_B0    (OFF_C1 + Nn*LHh)            // 512
#define OFF_B1    (OFF_B0 + GATES)             // 512
#define OFF_DEG   (OFF_B1 + GATES)             // (unused, kept for layout stability)
#define OFF_H0A   (OFF_DEG + Nn)               // N*128 f16 = N*64 float units
#define OFF_H0B   (OFF_H0A + Nn*64)
#define OFF_H1A   (OFF_H0B + Nn*64)
#define OFF_H1B   (OFF_H1A + Nn*64)
#define OFF_W0T   (OFF_H1B + Nn*64)            // 512*192 f16 = 49152 floats
#define OFF_W1T   (OFF_W0T + 512*192/2)        // 512*256 f16 = 65536 floats
#define OFF_END   (OFF_W1T + 512*256/2)

__device__ __forceinline__ float fsig(float x) { return 1.f / (1.f + __expf(-x)); }
__device__ __forceinline__ float ftanh(float x) { return 1.f - 2.f / (1.f + __expf(2.f * x)); }

// ---- prep: transpose weights to f16 [q][k], fold biases, zero deg replicas ----
// grid: [0,512) W0T | [512,1024) W1T | [1024,1028) biases | [1028,2028) degr zero
__global__ void prep_weights(const float* __restrict__ w_ih0, const float* __restrict__ w_hh0,
                             const float* __restrict__ b_ih0, const float* __restrict__ b_hh0,
                             const float* __restrict__ w_ih1, const float* __restrict__ w_hh1,
                             const float* __restrict__ b_ih1, const float* __restrict__ b_hh1,
                             f16* __restrict__ W0T, f16* __restrict__ W1T,
                             float* __restrict__ B0, float* __restrict__ B1,
                             int* __restrict__ degr) {
    int b = blockIdx.x, t = threadIdx.x;
    if (b < 512) {
        if (t < 192) {
            float v = (t < 64) ? w_ih0[b * 64 + t] : w_hh0[b * 128 + (t - 64)];
            W0T[b * 192 + t] = (f16)v;
        }
    } else if (b < 1024) {
        int q = b - 512;
        float v = (t < 128) ? w_ih1[q * 128 + t] : w_hh1[q * 128 + (t - 128)];
        W1T[q * 256 + t] = (f16)v;
    } else if (b < 1028) {
        int idx = (b - 1024) * 256 + t;
        if (idx < 512) B0[idx] = b_ih0[idx] + b_hh0[idx];
        else           B1[idx - 512] = b_ih1[idx - 512] + b_hh1[idx - 512];
    } else {
        int n = (b - 1028) * 256 + t;
        if (n < NREP * Nn) degr[n] = 0;
    }
}

// ---- degree count, replicated ----
__global__ void deg_count(const int* __restrict__ ei, int* __restrict__ degr) {
    int e = blockIdx.x * blockDim.x + threadIdx.x;
    if (e < Ee) atomicAdd(&degr[(blockIdx.x & (NREP - 1)) * Nn + ei[Ee + e]], 1);
}

// ---- dinv + init agg replicas (replica 0 = self-loop term, 1..NREP-1 = 0) ----
__global__ void agg_init(const float* __restrict__ x, const int* __restrict__ degr,
                         float* __restrict__ dinv, float* __restrict__ aggr) {
    int n = blockIdx.x * blockDim.x + threadIdx.x;
    if (n >= Nn) return;
    int deg = 1;  // self loop
    #pragma unroll
    for (int r = 0; r < NREP; ++r) deg += degr[r * Nn + n];
    float di = rsqrtf((float)deg);
    dinv[n] = di;
    float dd = di * di;
    #pragma unroll
    for (int t = 0; t < Tt; ++t) aggr[n * Tt + t] = x[n * Tt + t] * dd;
    for (int r = 1; r < NREP; ++r) {
        #pragma unroll
        for (int t = 0; t < Tt; ++t) aggr[r * (Nn * Tt) + n * Tt + t] = 0.f;
    }
}

// ---- edge scatter into replica blockIdx&15 ----
__global__ void edge_scatter(const float* __restrict__ x, const int* __restrict__ ei,
                             const float* __restrict__ dinv, float* __restrict__ aggr) {
    int e = blockIdx.x * blockDim.x + threadIdx.x;
    if (e >= Ee) return;
    int s = ei[e], d = ei[Ee + e];
    float cf = dinv[s] * dinv[d];
    float* base = aggr + (size_t)(blockIdx.x & (NREP - 1)) * (Nn * Tt) + (size_t)d * Tt;
    #pragma unroll
    for (int t = 0; t < Tt; ++t) atomicAdd(&base[t], x[s * Tt + t] * cf);
}

// ---- fold replicas -> final agg ----
__global__ void agg_reduce(const float* __restrict__ aggr, float* __restrict__ agg) {
    int i = blockIdx.x * blockDim.x + threadIdx.x;
    if (i >= Nn * Tt) return;
    float s = 0.f;
    #pragma unroll
    for (int r = 0; r < NREP; ++r) s += aggr[r * (Nn * Tt) + i];
    agg[i] = s;
}

// ---- fused LSTM step, MFMA f16 ----
// Block: 256 thr = 4 waves; wave = 16 nodes x 16 u x 4 gates (4 C-frags).
// Block tile: 32 nodes (blockIdx.x) x 32 u (blockIdx.y).
// X staged in LDS as f16 [node][k], row stride KT+8 (2-way bank aliasing = free).
// B-fragments read from global W[q][k] f16 (L2-resident, 16B/lane contiguous).
// launch_bounds (256,4): 128-VGPR budget — (256,6) risked scratch spills in the MFMA loop.
template <int K_IN, bool FIRST>
__global__ __launch_bounds__(256, 4) void lstm_mfma(
    const float* __restrict__ agg, int tcol,      // layer0 input source
    const f16* __restrict__ xin16,                // layer1 input (h0 current)
    const f16* __restrict__ hrec,                 // recurrent h (prev step), unused if FIRST
    const float* __restrict__ gw, const float* __restrict__ gb,  // gcn params (layer0)
    const f16* __restrict__ WT,                   // [512][KT] f16
    const float* __restrict__ bias,               // 512 folded biases
    f16* __restrict__ hout, float* __restrict__ c) {
    constexpr int KT = K_IN + 128;
    constexpr int S = KT + 8;                     // f16 row stride: 2-way bank aliasing only
    __shared__ f16 X[32 * S];
    const int tid = threadIdx.x;
    const int n0 = blockIdx.x * 32;
    const int ub = blockIdx.y * 32;

    // --- stage input cols 0..K_IN-1 ---
    if constexpr (K_IN == 64) {
        // generated GCN features: relu(gw[j]*agg[n][t] + gb[j]); 8 threads/node, 8 f16 each
        int node = tid >> 3, j0 = (tid & 7) * 8;
        float a = agg[(size_t)(n0 + node) * Tt + tcol];
        f16x8 v;
        #pragma unroll
        for (int j = 0; j < 8; ++j)
            v[j] = (f16)fmaxf(gw[j0 + j] * a + gb[j0 + j], 0.f);
        *(f16x8*)&X[node * S + j0] = v;
    } else {
        // h0 current, f16 [n][128]
        #pragma unroll
        for (int r = 0; r < 2; ++r) {
            int chunk = tid + 256 * r;
            int node = chunk >> 4, j0 = (chunk & 15) * 8;
            f16x8 v = *(const f16x8*)(xin16 + (size_t)(n0 + node) * 128 + j0);
            *(f16x8*)&X[node * S + j0] = v;
        }
    }
    // --- stage recurrent cols K_IN..K_IN+127 ---
    #pragma unroll
    for (int r = 0; r < 2; ++r) {
        int chunk = tid + 256 * r;
        int node = chunk >> 4, j0 = (chunk & 15) * 8;
        f16x8 v;
        if constexpr (FIRST) {
            #pragma unroll
            for (int j = 0; j < 8; ++j) v[j] = (f16)0.f;
        } else {
            v = *(const f16x8*)(hrec + (size_t)(n0 + node) * 128 + j0);
        }
        *(f16x8*)&X[node * S + K_IN + j0] = v;
    }
    __syncthreads();

    const int lane = tid & 63;
    const int wave = tid >> 6;
    const int l = lane & 15;           // A row / C col
    const int quad = lane >> 4;        // k-group / C row-group
    const int wn = wave & 1;           // node half (16)
    const int wu = wave >> 1;          // u half (16)
    const int ucol = ub + wu * 16 + l; // hidden unit 0..127

    const f16* ap = &X[(wn * 16 + l) * S + quad * 8];
    const f16* bp0 = WT + (size_t)(0 * 128 + ucol) * KT + quad * 8;
    const f16* bp1 = WT + (size_t)(1 * 128 + ucol) * KT + quad * 8;
    const f16* bp2 = WT + (size_t)(2 * 128 + ucol) * KT + quad * 8;
    const f16* bp3 = WT + (size_t)(3 * 128 + ucol) * KT + quad * 8;

    f32x4 acc0 = {0.f, 0.f, 0.f, 0.f}, acc1 = acc0, acc2 = acc0, acc3 = acc0;
    #pragma unroll
    for (int kt = 0; kt < KT / 32; ++kt) {
        f16x8 a = *(const f16x8*)(ap + kt * 32);
        f16x8 b0 = *(const f16x8*)(bp0 + kt * 32);
        f16x8 b1 = *(const f16x8*)(bp1 + kt * 32);
        f16x8 b2 = *(const f16x8*)(bp2 + kt * 32);
        f16x8 b3 = *(const f16x8*)(bp3 + kt * 32);
        acc0 = __builtin_amdgcn_mfma_f32_16x16x32_f16(a, b0, acc0, 0, 0, 0);
        acc1 = __builtin_amdgcn_mfma_f32_16x16x32_f16(a, b1, acc1, 0, 0, 0);
        acc2 = __builtin_amdgcn_mfma_f32_16x16x32_f16(a, b2, acc2, 0, 0, 0);
        acc3 = __builtin_amdgcn_mfma_f32_16x16x32_f16(a, b3, acc3, 0, 0, 0);
    }

    const float bi = bias[ucol], bf = bias[128 + ucol];
    const float bg = bias[256 + ucol], bo = bias[384 + ucol];
    #pragma unroll
    for (int r = 0; r < 4; ++r) {
        int node = n0 + wn * 16 + quad * 4 + r;   // C row = quad*4 + reg
        size_t off = (size_t)node * 128 + ucol;
        float co = FIRST ? 0.f : c[off];
        float i_ = fsig(acc0[r] + bi);
        float f_ = fsig(acc1[r] + bf);
        float g_ = ftanh(acc2[r] + bg);
        float o_ = fsig(acc3[r] + bo);
        float cn = f_ * co + i_ * g_;
        float hn = o_ * ftanh(cn);
        c[off] = cn;
        hout[off] = (f16)hn;
    }
}

// ---- head: out[n] = x[n,T-1] + relu(h1[n]@pw1.T+pb1)@pw2.T + pb2 ----
__global__ __launch_bounds__(256) void head_kernel(const float* __restrict__ x,
                                                   const f16* __restrict__ h1,
                                                   const float* __restrict__ pw1,
                                                   const float* __restrict__ pb1,
                                                   const float* __restrict__ pw2,
                                                   const float* __restrict__ pb2,
                                                   float* __restrict__ out) {
    int lane = threadIdx.x & 63;
    int node = blockIdx.x * 4 + (threadIdx.x >> 6);
    const f16x8* hp = (const f16x8*)(h1 + (size_t)node * 128);
    const float4* wp = (const float4*)(pw1 + (size_t)lane * 128);
    float s = pb1[lane];
    #pragma unroll
    for (int k8 = 0; k8 < 16; ++k8) {
        f16x8 hv = hp[k8];
        float4 w0 = wp[k8 * 2], w1 = wp[k8 * 2 + 1];
        s = fmaf((float)hv[0], w0.x, s); s = fmaf((float)hv[1], w0.y, s);
        s = fmaf((float)hv[2], w0.z, s); s = fmaf((float)hv[3], w0.w, s);
        s = fmaf((float)hv[4], w1.x, s); s = fmaf((float)hv[5], w1.y, s);
        s = fmaf((float)hv[6], w1.z, s); s = fmaf((float)hv[7], w1.w, s);
    }
    float y = fmaxf(s, 0.f) * pw2[lane];
    #pragma unroll
    for (int off = 32; off >= 1; off >>= 1) y += __shfl_down(y, off);
    if (lane == 0) out[node] = x[node * Tt + (Tt - 1)] + y + pb2[0];
}

extern "C" void kernel_launch(void* const* d_in, const int* in_sizes, int n_in,
                              void* d_out, int out_size, void* d_ws, size_t ws_size,
                              hipStream_t stream) {
    const float* x      = (const float*)d_in[0];
    const int*   ei     = (const int*)d_in[1];
    const float* gcn_w  = (const float*)d_in[2];
    const float* gcn_b  = (const float*)d_in[3];
    const float* w_ih0  = (const float*)d_in[4];
    const float* w_hh0  = (const float*)d_in[5];
    const float* b_ih0  = (const float*)d_in[6];
    const float* b_hh0  = (const float*)d_in[7];
    const float* w_ih1  = (const float*)d_in[8];
    const float* w_hh1  = (const float*)d_in[9];
    const float* b_ih1  = (const float*)d_in[10];
    const float* b_hh1  = (const float*)d_in[11];
    const float* pw1    = (const float*)d_in[12];
    const float* pb1    = (const float*)d_in[13];
    const float* pw2    = (const float*)d_in[14];
    const float* pb2    = (const float*)d_in[15];
    float* out = (float*)d_out;

    float* wsf  = (float*)d_ws;
    float* dinv = wsf + OFF_DINV;
    float* agg  = wsf + OFF_AGG;
    float* c0   = wsf + OFF_C0;
    float* c1   = wsf + OFF_C1;
    float* B0   = wsf + OFF_B0;
    float* B1   = wsf + OFF_B1;
    // replicas alias C0/C1 (dead until first lstm dispatch, which writes c without reading)
    float* aggr = c0;                 // NREP * N * 5 floats  (5.1 MB < 8 MB)
    int*   degr = (int*)c1;           // NREP * N ints        (1 MB   < 8 MB)
    f16*   h0b[2] = { (f16*)(wsf + OFF_H0A), (f16*)(wsf + OFF_H0B) };
    f16*   h1b[2] = { (f16*)(wsf + OFF_H1A), (f16*)(wsf + OFF_H1B) };
    f16*   W0T  = (f16*)(wsf + OFF_W0T);
    f16*   W1T  = (f16*)(wsf + OFF_W1T);

    // 1) prep weights (f16 transpose) + fold biases + zero deg replicas
    prep_weights<<<2028, 256, 0, stream>>>(w_ih0, w_hh0, b_ih0, b_hh0,
                                           w_ih1, w_hh1, b_ih1, b_hh1,
                                           W0T, W1T, B0, B1, degr);
    // 2) degree (replicated atomics)
    deg_count<<<(Ee + 255) / 256, 256, 0, stream>>>(ei, degr);
    // 3) dinv + agg replica init (replica 0 = self loop)
    agg_init<<<(Nn + 255) / 256, 256, 0, stream>>>(x, degr, dinv, aggr);
    // 4) edge scatter (replicated atomics)
    edge_scatter<<<(Ee + 255) / 256, 256, 0, stream>>>(x, ei, dinv, aggr);
    // 5) fold replicas
    agg_reduce<<<(Nn * Tt + 255) / 256, 256, 0, stream>>>(aggr, agg);

    // 6) LSTM: layer0 then layer1 per step; h double-buffered (u-split blocks
    //    read other blocks' h at staging -> in-place would race)
    dim3 grid(Nn / 32, 4);
    lstm_mfma<64, true ><<<grid, 256, 0, stream>>>(agg, 0, nullptr, nullptr,
                                                   gcn_w, gcn_b, W0T, B0, h0b[0], c0);
    lstm_mfma<128, true><<<grid, 256, 0, stream>>>(nullptr, 0, h0b[0], nullptr,
                                                   nullptr, nullptr, W1T, B1, h1b[0], c1);
    for (int t = 1; t < Tt; ++t) {
        lstm_mfma<64, false ><<<grid, 256, 0, stream>>>(agg, t, nullptr, h0b[(t - 1) & 1],
                                                        gcn_w, gcn_b, W0T, B0, h0b[t & 1], c0);
        lstm_mfma<128, false><<<grid, 256, 0, stream>>>(nullptr, 0, h0b[t & 1], h1b[(t - 1) & 1],
                                                        nullptr, nullptr, W1T, B1, h1b[t & 1], c1);
    }

    // 7) head (reads h1 of t=4 -> buffer index 0)
    head_kernel<<<Nn / 4, 256, 0, stream>>>(x, h1b[0], pw1, pb1, pw2, pb2, out);
}

// Round 5
// 337.365 us; speedup vs baseline: 2.5986x; 1.6324x over previous
//
#include <hip/hip_runtime.h>
#include <hip/hip_bf16.h>

// Problem constants (fixed by reference)
#define Nn 16000
#define Ee 256000
#define Tt 5
#define HIDd 64
#define LHh 128
#define GATES 512  // 4*LH
#define NREP 8     // one replica per XCD (XCC_ID-indexed)

typedef _Float16 f16;
typedef __attribute__((ext_vector_type(8))) _Float16 f16x8;
typedef __attribute__((ext_vector_type(4))) float f32x4;

// ---- workspace layout (float units) ----
#define OFF_DINV 0
#define OFF_AGG   (OFF_DINV + Nn)              // N*5 fp32 final, node-major [n][t]
#define OFF_C0    (OFF_AGG + Nn*Tt)            // N*128 fp32  (aliased early: agg replicas, NREP*N*5)
#define OFF_C1    (OFF_C0 + Nn*LHh)            // N*128 fp32  (aliased early: deg replicas, NREP*N ints)
#define OFF_B0    (OFF_C1 + Nn*LHh)            // 512
#define OFF_B1    (OFF_B0 + GATES)             // 512
#define OFF_DEG   (OFF_B1 + GATES)             // (layout spacer)
#define OFF_H0A   (OFF_DEG + Nn)               // N*128 f16 = N*64 float units
#define OFF_H0B   (OFF_H0A + Nn*64)
#define OFF_H1A   (OFF_H0B + Nn*64)
#define OFF_H1B   (OFF_H1A + Nn*64)
#define OFF_W0S   (OFF_H1B + Nn*64)            // 512*192 f16 = 49152 floats (swizzled)
#define OFF_W1S   (OFF_W0S + 512*192/2)        // 512*256 f16 = 65536 floats (swizzled)
#define OFF_END   (OFF_W1S + 512*256/2)

__device__ __forceinline__ float fsig(float x) { return 1.f / (1.f + __expf(-x)); }
__device__ __forceinline__ float ftanh(float x) { return 1.f - 2.f / (1.f + __expf(2.f * x)); }

__device__ __forceinline__ unsigned xcc_id() {
    unsigned x;
    asm volatile("s_getreg_b32 %0, hwreg(HW_REG_XCC_ID)" : "=s"(x));
    return x & (NREP - 1);
}

// ---- prep: swizzle weights to f16 MFMA-fragment order, fold biases, zero deg replicas ----
// Swizzled layout: chunk(g_u16, gate, kt) of 512 f16; within chunk lane(quad*16+l)*8 + j.
// q = gate*128 + g*16 + l ; k = kt*32 + quad*8 + j.
// grid: [0,512) W0S rows | [512,1024) W1S rows | [1024,1028) biases | [1028,1528) degr zero
__global__ void prep_weights(const float* __restrict__ w_ih0, const float* __restrict__ w_hh0,
                             const float* __restrict__ b_ih0, const float* __restrict__ b_hh0,
                             const float* __restrict__ w_ih1, const float* __restrict__ w_hh1,
                             const float* __restrict__ b_ih1, const float* __restrict__ b_hh1,
                             f16* __restrict__ W0S, f16* __restrict__ W1S,
                             float* __restrict__ B0, float* __restrict__ B1,
                             int* __restrict__ degr) {
    int b = blockIdx.x, t = threadIdx.x;
    if (b < 512) {
        if (t < 192) {
            int q = b, k = t;
            float v = (k < 64) ? w_ih0[q * 64 + k] : w_hh0[q * 128 + (k - 64)];
            int g = (q & 127) >> 4, l = q & 15, gate = q >> 7;
            int kt = k >> 5, quad = (k >> 3) & 3, j = k & 7;
            W0S[(((g * 4 + gate) * 6 + kt) * 64 + quad * 16 + l) * 8 + j] = (f16)v;
        }
    } else if (b < 1024) {
        int q = b - 512, k = t;
        float v = (k < 128) ? w_ih1[q * 128 + k] : w_hh1[q * 128 + (k - 128)];
        int g = (q & 127) >> 4, l = q & 15, gate = q >> 7;
        int kt = k >> 5, quad = (k >> 3) & 3, j = k & 7;
        W1S[(((g * 4 + gate) * 8 + kt) * 64 + quad * 16 + l) * 8 + j] = (f16)v;
    } else if (b < 1028) {
        int idx = (b - 1024) * 256 + t;
        if (idx < 512) B0[idx] = b_ih0[idx] + b_hh0[idx];
        else           B1[idx - 512] = b_ih1[idx - 512] + b_hh1[idx - 512];
    } else {
        int n = (b - 1028) * 256 + t;
        if (n < NREP * Nn) degr[n] = 0;
    }
}

// ---- degree count: XCD-local replica, workgroup-scope atomic (executes in local L2) ----
__global__ void deg_count(const int* __restrict__ ei, int* __restrict__ degr) {
    int e = blockIdx.x * blockDim.x + threadIdx.x;
    if (e >= Ee) return;
    int* p = &degr[xcc_id() * Nn + ei[Ee + e]];
    __hip_atomic_fetch_add(p, 1, __ATOMIC_RELAXED, __HIP_MEMORY_SCOPE_WORKGROUP);
}

// ---- dinv + init agg replicas (replica 0 = self-loop term, others 0) ----
__global__ void agg_init(const float* __restrict__ x, const int* __restrict__ degr,
                         float* __restrict__ dinv, float* __restrict__ aggr) {
    int n = blockIdx.x * blockDim.x + threadIdx.x;
    if (n >= Nn) return;
    int deg = 1;  // self loop
    #pragma unroll
    for (int r = 0; r < NREP; ++r) deg += degr[r * Nn + n];
    float di = rsqrtf((float)deg);
    dinv[n] = di;
    float dd = di * di;
    #pragma unroll
    for (int t = 0; t < Tt; ++t) aggr[n * Tt + t] = x[n * Tt + t] * dd;
    #pragma unroll
    for (int r = 1; r < NREP; ++r) {
        #pragma unroll
        for (int t = 0; t < Tt; ++t) aggr[r * (Nn * Tt) + n * Tt + t] = 0.f;
    }
}

// ---- edge scatter: one (edge,t) per thread; XCD-local replica, workgroup-scope atomic ----
__global__ void edge_scatter(const float* __restrict__ x, const int* __restrict__ ei,
                             const float* __restrict__ dinv, float* __restrict__ aggr) {
    int idx = blockIdx.x * blockDim.x + threadIdx.x;
    if (idx >= Ee * Tt) return;
    int e = idx / Tt, t = idx - e * Tt;
    int s = ei[e], d = ei[Ee + e];
    float v = x[s * Tt + t] * dinv[s] * dinv[d];
    float* p = aggr + (size_t)xcc_id() * (Nn * Tt) + (size_t)d * Tt + t;
    __hip_atomic_fetch_add(p, v, __ATOMIC_RELAXED, __HIP_MEMORY_SCOPE_WORKGROUP);
}

// ---- fold replicas -> final agg ----
__global__ void agg_reduce(const float* __restrict__ aggr, float* __restrict__ agg) {
    int i = blockIdx.x * blockDim.x + threadIdx.x;
    if (i >= Nn * Tt) return;
    float s = 0.f;
    #pragma unroll
    for (int r = 0; r < NREP; ++r) s += aggr[r * (Nn * Tt) + i];
    agg[i] = s;
}

// ---- fused LSTM step, MFMA f16 ----
// Block tile: 64 nodes (blockIdx.x) x 32 u (blockIdx.y); 256 thr = 4 waves.
// Wave w: u-tile (w&1), node-tiles {2*(w>>1), 2*(w>>1)+1}; 4 gates -> 8 C-frags/wave.
// X in LDS f16 [node][k], row stride KT+8. B-frags from swizzled WS: every load is
// lane-contiguous 1KB (8x128B transactions, vs 64x64B with the naive [q][k] layout).
template <int K_IN, bool FIRST>
__global__ __launch_bounds__(256, 4) void lstm_mfma(
    const float* __restrict__ agg, int tcol,      // layer0 input source
    const f16* __restrict__ xin16,                // layer1 input (h0 current)
    const f16* __restrict__ hrec,                 // recurrent h (prev step)
    const float* __restrict__ gw, const float* __restrict__ gb,  // gcn params (layer0)
    const f16* __restrict__ WS,                   // swizzled weights
    const float* __restrict__ bias,               // 512 folded biases
    f16* __restrict__ hout, float* __restrict__ c) {
    constexpr int KT = K_IN + 128;
    constexpr int NKT = KT / 32;
    constexpr int S = KT + 8;
    __shared__ f16 X[64 * S];
    const int tid = threadIdx.x;
    const int n0 = blockIdx.x * 64;
    const int ub = blockIdx.y;                    // u-block: 32 u

    // --- stage input cols 0..K_IN-1 ---
    if constexpr (K_IN == 64) {
        // 64 nodes x 64 j = 512 f16x8 chunks; 2 per thread
        #pragma unroll
        for (int r = 0; r < 2; ++r) {
            int chunk = tid + 256 * r;
            int node = chunk >> 3, j0 = (chunk & 7) * 8;
            float a = agg[(size_t)(n0 + node) * Tt + tcol];
            f16x8 v;
            #pragma unroll
            for (int j = 0; j < 8; ++j)
                v[j] = (f16)fmaxf(gw[j0 + j] * a + gb[j0 + j], 0.f);
            *(f16x8*)&X[node * S + j0] = v;
        }
    } else {
        // 64 nodes x 128 k = 1024 chunks; 4 per thread
        #pragma unroll
        for (int r = 0; r < 4; ++r) {
            int chunk = tid + 256 * r;
            int node = chunk >> 4, j0 = (chunk & 15) * 8;
            f16x8 v = *(const f16x8*)(xin16 + (size_t)(n0 + node) * 128 + j0);
            *(f16x8*)&X[node * S + j0] = v;
        }
    }
    // --- stage recurrent cols K_IN..K_IN+127 ---
    #pragma unroll
    for (int r = 0; r < 4; ++r) {
        int chunk = tid + 256 * r;
        int node = chunk >> 4, j0 = (chunk & 15) * 8;
        f16x8 v;
        if constexpr (FIRST) {
            #pragma unroll
            for (int j = 0; j < 8; ++j) v[j] = (f16)0.f;
        } else {
            v = *(const f16x8*)(hrec + (size_t)(n0 + node) * 128 + j0);
        }
        *(f16x8*)&X[node * S + K_IN + j0] = v;
    }
    __syncthreads();

    const int lane = tid & 63;
    const int wave = tid >> 6;
    const int l = lane & 15;
    const int quad = lane >> 4;
    const int ut = wave & 1;           // u-tile within block
    const int np = wave >> 1;          // node-pair (2 tiles of 16)
    const int gg = ub * 2 + ut;        // global u16-group (0..7)
    const int ucol = ub * 32 + ut * 16 + l;

    const f16* ap0 = &X[(np * 32 + l) * S + quad * 8];
    const f16* ap1 = ap0 + 16 * S;
    const f16* bbase = WS + ((size_t)(gg * 4) * NKT) * 512 + lane * 8;

    f32x4 acc[2][4];
    #pragma unroll
    for (int i = 0; i < 2; ++i)
        #pragma unroll
        for (int g = 0; g < 4; ++g) acc[i][g] = (f32x4){0.f, 0.f, 0.f, 0.f};

    #pragma unroll
    for (int kt = 0; kt < NKT; ++kt) {
        f16x8 a0 = *(const f16x8*)(ap0 + kt * 32);
        f16x8 a1 = *(const f16x8*)(ap1 + kt * 32);
        #pragma unroll
        for (int g = 0; g < 4; ++g) {
            f16x8 b = *(const f16x8*)(bbase + (size_t)(g * NKT + kt) * 512);
            acc[0][g] = __builtin_amdgcn_mfma_f32_16x16x32_f16(a0, b, acc[0][g], 0, 0, 0);
            acc[1][g] = __builtin_amdgcn_mfma_f32_16x16x32_f16(a1, b, acc[1][g], 0, 0, 0);
        }
    }

    const float bi = bias[ucol], bf = bias[128 + ucol];
    const float bg = bias[256 + ucol], bo = bias[384 + ucol];
    #pragma unroll
    for (int i = 0; i < 2; ++i) {
        #pragma unroll
        for (int r = 0; r < 4; ++r) {
            int node = n0 + (np * 2 + i) * 16 + quad * 4 + r;   // C row = quad*4 + reg
            size_t off = (size_t)node * 128 + ucol;
            float co = FIRST ? 0.f : c[off];
            float i_ = fsig(acc[i][0][r] + bi);
            float f_ = fsig(acc[i][1][r] + bf);
            float g_ = ftanh(acc[i][2][r] + bg);
            float o_ = fsig(acc[i][3][r] + bo);
            float cn = f_ * co + i_ * g_;
            float hn = o_ * ftanh(cn);
            c[off] = cn;
            hout[off] = (f16)hn;
        }
    }
}

// ---- head: out[n] = x[n,T-1] + relu(h1[n]@pw1.T+pb1)@pw2.T + pb2 ----
__global__ __launch_bounds__(256) void head_kernel(const float* __restrict__ x,
                                                   const f16* __restrict__ h1,
                                                   const float* __restrict__ pw1,
                                                   const float* __restrict__ pb1,
                                                   const float* __restrict__ pw2,
                                                   const float* __restrict__ pb2,
                                                   float* __restrict__ out) {
    int lane = threadIdx.x & 63;
    int node = blockIdx.x * 4 + (threadIdx.x >> 6);
    const f16x8* hp = (const f16x8*)(h1 + (size_t)node * 128);
    const float4* wp = (const float4*)(pw1 + (size_t)lane * 128);
    float s = pb1[lane];
    #pragma unroll
    for (int k8 = 0; k8 < 16; ++k8) {
        f16x8 hv = hp[k8];
        float4 w0 = wp[k8 * 2], w1 = wp[k8 * 2 + 1];
        s = fmaf((float)hv[0], w0.x, s); s = fmaf((float)hv[1], w0.y, s);
        s = fmaf((float)hv[2], w0.z, s); s = fmaf((float)hv[3], w0.w, s);
        s = fmaf((float)hv[4], w1.x, s); s = fmaf((float)hv[5], w1.y, s);
        s = fmaf((float)hv[6], w1.z, s); s = fmaf((float)hv[7], w1.w, s);
    }
    float y = fmaxf(s, 0.f) * pw2[lane];
    #pragma unroll
    for (int off = 32; off >= 1; off >>= 1) y += __shfl_down(y, off);
    if (lane == 0) out[node] = x[node * Tt + (Tt - 1)] + y + pb2[0];
}

extern "C" void kernel_launch(void* const* d_in, const int* in_sizes, int n_in,
                              void* d_out, int out_size, void* d_ws, size_t ws_size,
                              hipStream_t stream) {
    const float* x      = (const float*)d_in[0];
    const int*   ei     = (const int*)d_in[1];
    const float* gcn_w  = (const float*)d_in[2];
    const float* gcn_b  = (const float*)d_in[3];
    const float* w_ih0  = (const float*)d_in[4];
    const float* w_hh0  = (const float*)d_in[5];
    const float* b_ih0  = (const float*)d_in[6];
    const float* b_hh0  = (const float*)d_in[7];
    const float* w_ih1  = (const float*)d_in[8];
    const float* w_hh1  = (const float*)d_in[9];
    const float* b_ih1  = (const float*)d_in[10];
    const float* b_hh1  = (const float*)d_in[11];
    const float* pw1    = (const float*)d_in[12];
    const float* pb1    = (const float*)d_in[13];
    const float* pw2    = (const float*)d_in[14];
    const float* pb2    = (const float*)d_in[15];
    float* out = (float*)d_out;

    float* wsf  = (float*)d_ws;
    float* dinv = wsf + OFF_DINV;
    float* agg  = wsf + OFF_AGG;
    float* c0   = wsf + OFF_C0;
    float* c1   = wsf + OFF_C1;
    float* B0   = wsf + OFF_B0;
    float* B1   = wsf + OFF_B1;
    // replicas alias C0/C1 (dead until first lstm dispatch, which writes c without reading)
    float* aggr = c0;                 // NREP * N * 5 floats (2.56 MB < 8 MB)
    int*   degr = (int*)c1;           // NREP * N ints      (0.51 MB < 8 MB)
    f16*   h0b[2] = { (f16*)(wsf + OFF_H0A), (f16*)(wsf + OFF_H0B) };
    f16*   h1b[2] = { (f16*)(wsf + OFF_H1A), (f16*)(wsf + OFF_H1B) };
    f16*   W0S  = (f16*)(wsf + OFF_W0S);
    f16*   W1S  = (f16*)(wsf + OFF_W1S);

    // 1) prep weights (swizzled f16) + fold biases + zero deg replicas
    prep_weights<<<1528, 256, 0, stream>>>(w_ih0, w_hh0, b_ih0, b_hh0,
                                           w_ih1, w_hh1, b_ih1, b_hh1,
                                           W0S, W1S, B0, B1, degr);
    // 2) degree (XCD-local atomics)
    deg_count<<<(Ee + 255) / 256, 256, 0, stream>>>(ei, degr);
    // 3) dinv + agg replica init
    agg_init<<<(Nn + 255) / 256, 256, 0, stream>>>(x, degr, dinv, aggr);
    // 4) edge scatter: one (edge,t) per thread, XCD-local atomics
    edge_scatter<<<(Ee * Tt + 255) / 256, 256, 0, stream>>>(x, ei, dinv, aggr);
    // 5) fold replicas
    agg_reduce<<<(Nn * Tt + 255) / 256, 256, 0, stream>>>(aggr, agg);

    // 6) LSTM: layer0 then layer1 per step; h double-buffered (u-split blocks
    //    read full-k hrec while others write hout -> in-place would race)
    dim3 grid(Nn / 64, 4);
    lstm_mfma<64, true ><<<grid, 256, 0, stream>>>(agg, 0, nullptr, nullptr,
                                                   gcn_w, gcn_b, W0S, B0, h0b[0], c0);
    lstm_mfma<128, true><<<grid, 256, 0, stream>>>(nullptr, 0, h0b[0], nullptr,
                                                   nullptr, nullptr, W1S, B1, h1b[0], c1);
    for (int t = 1; t < Tt; ++t) {
        lstm_mfma<64, false ><<<grid, 256, 0, stream>>>(agg, t, nullptr, h0b[(t - 1) & 1],
                                                        gcn_w, gcn_b, W0S, B0, h0b[t & 1], c0);
        lstm_mfma<128, false><<<grid, 256, 0, stream>>>(nullptr, 0, h0b[t & 1], h1b[(t - 1) & 1],
                                                        nullptr, nullptr, W1S, B1, h1b[t & 1], c1);
    }

    // 7) head (reads h1 of t=4 -> buffer index 0)
    head_kernel<<<Nn / 4, 256, 0, stream>>>(x, h1b[0], pw1, pb1, pw2, pb2, out);
}

// Round 6
// 275.756 us; speedup vs baseline: 3.1791x; 1.2234x over previous
//
#include <hip/hip_runtime.h>
#include <hip/hip_bf16.h>

// Problem constants (fixed by reference)
#define Nn 16000
#define Ee 256000
#define Tt 5
#define HIDd 64
#define LHh 128
#define GATES 512  // 4*LH
#define NREP 8     // one replica per XCD (XCC_ID-indexed)

typedef _Float16 f16;
typedef __attribute__((ext_vector_type(8))) _Float16 f16x8;
typedef __attribute__((ext_vector_type(4))) float f32x4;

// ---- workspace layout (float units) ----
#define OFF_DINV 0
#define OFF_AGG   (OFF_DINV + Nn)              // N*5 fp32 final, node-major [n][t]
#define OFF_C0    (OFF_AGG + Nn*Tt)            // N*128 f16 (aliased early: agg replicas, NREP*N*5 fp32)
#define OFF_C1    (OFF_C0 + Nn*64)             // N*128 f16 (aliased early: deg replicas, NREP*N ints)
#define OFF_B0    (OFF_C1 + Nn*64)             // 512
#define OFF_B1    (OFF_B0 + GATES)             // 512
#define OFF_H0A   (OFF_B1 + GATES)             // N*128 f16 = N*64 float units
#define OFF_H0B   (OFF_H0A + Nn*64)
#define OFF_H1A   (OFF_H0B + Nn*64)
#define OFF_H1B   (OFF_H1A + Nn*64)
#define OFF_W0S   (OFF_H1B + Nn*64)            // 512*192 f16 (swizzled)
#define OFF_W1S   (OFF_W0S + 512*192/2)        // 512*256 f16 (swizzled)
#define OFF_PWS   (OFF_W1S + 512*256/2)        // 64*128 f16 (swizzled head weights)
#define OFF_END   (OFF_PWS + 64*128/2)

__device__ __forceinline__ float fsig(float x) { return 1.f / (1.f + __expf(-x)); }
__device__ __forceinline__ float ftanh(float x) { return 1.f - 2.f / (1.f + __expf(2.f * x)); }

__device__ __forceinline__ unsigned xcc_id() {
    unsigned x;
    asm volatile("s_getreg_b32 %0, hwreg(HW_REG_XCC_ID)" : "=s"(x));
    return x & (NREP - 1);
}

// ---- prep: swizzle weights to f16 MFMA-fragment order, fold biases, zero deg replicas ----
// Swizzle (B-frag order): q-tile g, k-tile kt; chunk(g,gate,kt) of 512 f16;
// within chunk lane(quad*16+l)*8 + j ;  q = gate*128+g*16+l ; k = kt*32+quad*8+j.
// grid: [0,512) W0S | [512,1024) W1S | [1024,1028) biases | [1028,1092) pwS | rest degr zero
__global__ void prep_weights(const float* __restrict__ w_ih0, const float* __restrict__ w_hh0,
                             const float* __restrict__ b_ih0, const float* __restrict__ b_hh0,
                             const float* __restrict__ w_ih1, const float* __restrict__ w_hh1,
                             const float* __restrict__ b_ih1, const float* __restrict__ b_hh1,
                             const float* __restrict__ pw1,
                             f16* __restrict__ W0S, f16* __restrict__ W1S, f16* __restrict__ pwS,
                             float* __restrict__ B0, float* __restrict__ B1,
                             int* __restrict__ degr) {
    int b = blockIdx.x, t = threadIdx.x;
    if (b < 512) {
        if (t < 192) {
            int q = b, k = t;
            float v = (k < 64) ? w_ih0[q * 64 + k] : w_hh0[q * 128 + (k - 64)];
            int g = (q & 127) >> 4, l = q & 15, gate = q >> 7;
            int kt = k >> 5, quad = (k >> 3) & 3, j = k & 7;
            W0S[(((g * 4 + gate) * 6 + kt) * 64 + quad * 16 + l) * 8 + j] = (f16)v;
        }
    } else if (b < 1024) {
        int q = b - 512, k = t;
        float v = (k < 128) ? w_ih1[q * 128 + k] : w_hh1[q * 128 + (k - 128)];
        int g = (q & 127) >> 4, l = q & 15, gate = q >> 7;
        int kt = k >> 5, quad = (k >> 3) & 3, j = k & 7;
        W1S[(((g * 4 + gate) * 8 + kt) * 64 + quad * 16 + l) * 8 + j] = (f16)v;
    } else if (b < 1028) {
        int idx = (b - 1024) * 256 + t;
        if (idx < 512) B0[idx] = b_ih0[idx] + b_hh0[idx];
        else           B1[idx - 512] = b_ih1[idx - 512] + b_hh1[idx - 512];
    } else if (b < 1092) {
        if (t < 128) {
            int u = b - 1028, k = t;
            int g = u >> 4, lp = u & 15;
            int kt = k >> 5, quad = (k >> 3) & 3, j = k & 7;
            pwS[((g * 4 + kt) * 64 + quad * 16 + lp) * 8 + j] = (f16)pw1[u * 128 + k];
        }
    } else {
        int n = (b - 1092) * 256 + t;
        if (n < NREP * Nn) degr[n] = 0;
    }
}

// ---- degree count: XCD-local replica, workgroup-scope atomic (executes in local L2) ----
__global__ void deg_count(const int* __restrict__ ei, int* __restrict__ degr) {
    int e = blockIdx.x * blockDim.x + threadIdx.x;
    if (e >= Ee) return;
    int* p = &degr[xcc_id() * Nn + ei[Ee + e]];
    __hip_atomic_fetch_add(p, 1, __ATOMIC_RELAXED, __HIP_MEMORY_SCOPE_WORKGROUP);
}

// ---- dinv + init agg replicas (replica 0 = self-loop term, others 0) ----
__global__ void agg_init(const float* __restrict__ x, const int* __restrict__ degr,
                         float* __restrict__ dinv, float* __restrict__ aggr) {
    int n = blockIdx.x * blockDim.x + threadIdx.x;
    if (n >= Nn) return;
    int deg = 1;  // self loop
    #pragma unroll
    for (int r = 0; r < NREP; ++r) deg += degr[r * Nn + n];
    float di = rsqrtf((float)deg);
    dinv[n] = di;
    float dd = di * di;
    #pragma unroll
    for (int t = 0; t < Tt; ++t) aggr[n * Tt + t] = x[n * Tt + t] * dd;
    #pragma unroll
    for (int r = 1; r < NREP; ++r) {
        #pragma unroll
        for (int t = 0; t < Tt; ++t) aggr[r * (Nn * Tt) + n * Tt + t] = 0.f;
    }
}

// ---- edge scatter: one (edge,t) per thread; XCD-local replica, workgroup-scope atomic ----
__global__ void edge_scatter(const float* __restrict__ x, const int* __restrict__ ei,
                             const float* __restrict__ dinv, float* __restrict__ aggr) {
    int idx = blockIdx.x * blockDim.x + threadIdx.x;
    if (idx >= Ee * Tt) return;
    int e = idx / Tt, t = idx - e * Tt;
    int s = ei[e], d = ei[Ee + e];
    float v = x[s * Tt + t] * dinv[s] * dinv[d];
    float* p = aggr + (size_t)xcc_id() * (Nn * Tt) + (size_t)d * Tt + t;
    __hip_atomic_fetch_add(p, v, __ATOMIC_RELAXED, __HIP_MEMORY_SCOPE_WORKGROUP);
}

// ---- fold replicas -> final agg ----
__global__ void agg_reduce(const float* __restrict__ aggr, float* __restrict__ agg) {
    int i = blockIdx.x * blockDim.x + threadIdx.x;
    if (i >= Nn * Tt) return;
    float s = 0.f;
    #pragma unroll
    for (int r = 0; r < NREP; ++r) s += aggr[r * (Nn * Tt) + i];
    agg[i] = s;
}

// ---- fused LSTM step, MFMA f16 ----
// Block tile: 64 nodes (blockIdx.x) x 32 u (blockIdx.y); 256 thr = 4 waves.
// Wave w: u-tile (w&1), node-tiles {2*(w>>1), 2*(w>>1)+1}; 4 gates -> 8 C-frags/wave.
// X in LDS f16 [node][k], row stride KT+8. B-frags from swizzled WS (lane-contiguous 1KB loads).
// c stored f16 (bounded values; halves c HBM round-trip).
template <int K_IN, bool FIRST>
__global__ __launch_bounds__(256, 4) void lstm_mfma(
    const float* __restrict__ agg, int tcol,      // layer0 input source
    const f16* __restrict__ xin16,                // layer1 input (h0 current)
    const f16* __restrict__ hrec,                 // recurrent h (prev step)
    const float* __restrict__ gw, const float* __restrict__ gb,  // gcn params (layer0)
    const f16* __restrict__ WS,                   // swizzled weights
    const float* __restrict__ bias,               // 512 folded biases
    f16* __restrict__ hout, f16* __restrict__ c) {
    constexpr int KT = K_IN + 128;
    constexpr int NKT = KT / 32;
    constexpr int S = KT + 8;
    __shared__ f16 X[64 * S];
    const int tid = threadIdx.x;
    const int n0 = blockIdx.x * 64;
    const int ub = blockIdx.y;                    // u-block: 32 u

    // --- stage input cols 0..K_IN-1 ---
    if constexpr (K_IN == 64) {
        #pragma unroll
        for (int r = 0; r < 2; ++r) {
            int chunk = tid + 256 * r;
            int node = chunk >> 3, j0 = (chunk & 7) * 8;
            float a = agg[(size_t)(n0 + node) * Tt + tcol];
            f16x8 v;
            #pragma unroll
            for (int j = 0; j < 8; ++j)
                v[j] = (f16)fmaxf(gw[j0 + j] * a + gb[j0 + j], 0.f);
            *(f16x8*)&X[node * S + j0] = v;
        }
    } else {
        #pragma unroll
        for (int r = 0; r < 4; ++r) {
            int chunk = tid + 256 * r;
            int node = chunk >> 4, j0 = (chunk & 15) * 8;
            f16x8 v = *(const f16x8*)(xin16 + (size_t)(n0 + node) * 128 + j0);
            *(f16x8*)&X[node * S + j0] = v;
        }
    }
    // --- stage recurrent cols K_IN..K_IN+127 ---
    #pragma unroll
    for (int r = 0; r < 4; ++r) {
        int chunk = tid + 256 * r;
        int node = chunk >> 4, j0 = (chunk & 15) * 8;
        f16x8 v;
        if constexpr (FIRST) {
            #pragma unroll
            for (int j = 0; j < 8; ++j) v[j] = (f16)0.f;
        } else {
            v = *(const f16x8*)(hrec + (size_t)(n0 + node) * 128 + j0);
        }
        *(f16x8*)&X[node * S + K_IN + j0] = v;
    }
    __syncthreads();

    const int lane = tid & 63;
    const int wave = tid >> 6;
    const int l = lane & 15;
    const int quad = lane >> 4;
    const int ut = wave & 1;           // u-tile within block
    const int np = wave >> 1;          // node-pair (2 tiles of 16)
    const int gg = ub * 2 + ut;        // global u16-group (0..7)
    const int ucol = ub * 32 + ut * 16 + l;

    const f16* ap0 = &X[(np * 32 + l) * S + quad * 8];
    const f16* ap1 = ap0 + 16 * S;
    const f16* bbase = WS + ((size_t)(gg * 4) * NKT) * 512 + lane * 8;

    f32x4 acc[2][4];
    #pragma unroll
    for (int i = 0; i < 2; ++i)
        #pragma unroll
        for (int g = 0; g < 4; ++g) acc[i][g] = (f32x4){0.f, 0.f, 0.f, 0.f};

    #pragma unroll
    for (int kt = 0; kt < NKT; ++kt) {
        f16x8 a0 = *(const f16x8*)(ap0 + kt * 32);
        f16x8 a1 = *(const f16x8*)(ap1 + kt * 32);
        #pragma unroll
        for (int g = 0; g < 4; ++g) {
            f16x8 b = *(const f16x8*)(bbase + (size_t)(g * NKT + kt) * 512);
            acc[0][g] = __builtin_amdgcn_mfma_f32_16x16x32_f16(a0, b, acc[0][g], 0, 0, 0);
            acc[1][g] = __builtin_amdgcn_mfma_f32_16x16x32_f16(a1, b, acc[1][g], 0, 0, 0);
        }
    }

    const float bi = bias[ucol], bf = bias[128 + ucol];
    const float bg = bias[256 + ucol], bo = bias[384 + ucol];
    #pragma unroll
    for (int i = 0; i < 2; ++i) {
        #pragma unroll
        for (int r = 0; r < 4; ++r) {
            int node = n0 + (np * 2 + i) * 16 + quad * 4 + r;   // C row = quad*4 + reg
            size_t off = (size_t)node * 128 + ucol;
            float co = FIRST ? 0.f : (float)c[off];
            float i_ = fsig(acc[i][0][r] + bi);
            float f_ = fsig(acc[i][1][r] + bf);
            float g_ = ftanh(acc[i][2][r] + bg);
            float o_ = fsig(acc[i][3][r] + bo);
            float cn = f_ * co + i_ * g_;
            float hn = o_ * ftanh(cn);
            c[off] = (f16)cn;
            hout[off] = (f16)hn;
        }
    }
}

// ---- head, MFMA: out = x[:,4] + relu(h1@pw1.T+pb1)@pw2.T + pb2 ----
// Wave = 16 nodes; A-frags straight from global h1 (coalesced, L2-resident);
// B-frags from swizzled pwS (lane-contiguous 1KB). D: u = lane&15 (col),
// node = quad*4+r (row). xor-butterfly over the 16 u-lanes reduces GEMM2.
__global__ __launch_bounds__(256) void head_mfma(const float* __restrict__ x,
                                                 const f16* __restrict__ h1,
                                                 const f16* __restrict__ pwS,
                                                 const float* __restrict__ pb1,
                                                 const float* __restrict__ pw2,
                                                 const float* __restrict__ pb2,
                                                 float* __restrict__ out) {
    const int lane = threadIdx.x & 63;
    const int wave = threadIdx.x >> 6;
    const int n0 = blockIdx.x * 64 + wave * 16;
    const int l = lane & 15, quad = lane >> 4;

    const f16* ap = h1 + (size_t)(n0 + l) * 128 + quad * 8;
    const f16* bp = pwS + lane * 8;

    f32x4 acc[4];
    #pragma unroll
    for (int g = 0; g < 4; ++g) acc[g] = (f32x4){0.f, 0.f, 0.f, 0.f};
    #pragma unroll
    for (int kt = 0; kt < 4; ++kt) {
        f16x8 a = *(const f16x8*)(ap + kt * 32);
        #pragma unroll
        for (int g = 0; g < 4; ++g) {
            f16x8 b = *(const f16x8*)(bp + (size_t)(g * 4 + kt) * 512);
            acc[g] = __builtin_amdgcn_mfma_f32_16x16x32_f16(a, b, acc[g], 0, 0, 0);
        }
    }

    // per-lane u = g*16 + l ; per-reg node = quad*4 + r
    float yr[4] = {0.f, 0.f, 0.f, 0.f};
    #pragma unroll
    for (int g = 0; g < 4; ++g) {
        float pb = pb1[g * 16 + l];
        float pw = pw2[g * 16 + l];
        #pragma unroll
        for (int r = 0; r < 4; ++r)
            yr[r] += fmaxf(acc[g][r] + pb, 0.f) * pw;
    }
    // reduce over the 16 u-lanes (xor masks stay within the quad group)
    #pragma unroll
    for (int m = 1; m <= 8; m <<= 1) {
        #pragma unroll
        for (int r = 0; r < 4; ++r) yr[r] += __shfl_xor(yr[r], m);
    }
    if (l < 4) {
        float v = (l == 0) ? yr[0] : (l == 1) ? yr[1] : (l == 2) ? yr[2] : yr[3];
        int node = n0 + quad * 4 + l;
        out[node] = x[node * Tt + (Tt - 1)] + v + pb2[0];
    }
}

extern "C" void kernel_launch(void* const* d_in, const int* in_sizes, int n_in,
                              void* d_out, int out_size, void* d_ws, size_t ws_size,
                              hipStream_t stream) {
    const float* x      = (const float*)d_in[0];
    const int*   ei     = (const int*)d_in[1];
    const float* gcn_w  = (const float*)d_in[2];
    const float* gcn_b  = (const float*)d_in[3];
    const float* w_ih0  = (const float*)d_in[4];
    const float* w_hh0  = (const float*)d_in[5];
    const float* b_ih0  = (const float*)d_in[6];
    const float* b_hh0  = (const float*)d_in[7];
    const float* w_ih1  = (const float*)d_in[8];
    const float* w_hh1  = (const float*)d_in[9];
    const float* b_ih1  = (const float*)d_in[10];
    const float* b_hh1  = (const float*)d_in[11];
    const float* pw1    = (const float*)d_in[12];
    const float* pb1    = (const float*)d_in[13];
    const float* pw2    = (const float*)d_in[14];
    const float* pb2    = (const float*)d_in[15];
    float* out = (float*)d_out;

    float* wsf  = (float*)d_ws;
    float* dinv = wsf + OFF_DINV;
    float* agg  = wsf + OFF_AGG;
    f16*   c0   = (f16*)(wsf + OFF_C0);
    f16*   c1   = (f16*)(wsf + OFF_C1);
    float* B0   = wsf + OFF_B0;
    float* B1   = wsf + OFF_B1;
    // replicas alias C0/C1 (dead until first lstm dispatch, which writes c without reading)
    float* aggr = (float*)c0;         // NREP*N*5 floats (2.56 MB < 4 MB region)
    int*   degr = (int*)c1;           // NREP*N ints     (0.51 MB < 4 MB region)
    f16*   h0b[2] = { (f16*)(wsf + OFF_H0A), (f16*)(wsf + OFF_H0B) };
    f16*   h1b[2] = { (f16*)(wsf + OFF_H1A), (f16*)(wsf + OFF_H1B) };
    f16*   W0S  = (f16*)(wsf + OFF_W0S);
    f16*   W1S  = (f16*)(wsf + OFF_W1S);
    f16*   pwS  = (f16*)(wsf + OFF_PWS);

    // 1) prep weights (swizzled f16, incl. head pw1) + fold biases + zero deg replicas
    prep_weights<<<1592, 256, 0, stream>>>(w_ih0, w_hh0, b_ih0, b_hh0,
                                           w_ih1, w_hh1, b_ih1, b_hh1, pw1,
                                           W0S, W1S, pwS, B0, B1, degr);
    // 2) degree (XCD-local atomics)
    deg_count<<<(Ee + 255) / 256, 256, 0, stream>>>(ei, degr);
    // 3) dinv + agg replica init
    agg_init<<<(Nn + 255) / 256, 256, 0, stream>>>(x, degr, dinv, aggr);
    // 4) edge scatter: one (edge,t) per thread, XCD-local atomics
    edge_scatter<<<(Ee * Tt + 255) / 256, 256, 0, stream>>>(x, ei, dinv, aggr);
    // 5) fold replicas
    agg_reduce<<<(Nn * Tt + 255) / 256, 256, 0, stream>>>(aggr, agg);

    // 6) LSTM: layer0 then layer1 per step; h double-buffered
    dim3 grid(Nn / 64, 4);
    lstm_mfma<64, true ><<<grid, 256, 0, stream>>>(agg, 0, nullptr, nullptr,
                                                   gcn_w, gcn_b, W0S, B0, h0b[0], c0);
    lstm_mfma<128, true><<<grid, 256, 0, stream>>>(nullptr, 0, h0b[0], nullptr,
                                                   nullptr, nullptr, W1S, B1, h1b[0], c1);
    for (int t = 1; t < Tt; ++t) {
        lstm_mfma<64, false ><<<grid, 256, 0, stream>>>(agg, t, nullptr, h0b[(t - 1) & 1],
                                                        gcn_w, gcn_b, W0S, B0, h0b[t & 1], c0);
        lstm_mfma<128, false><<<grid, 256, 0, stream>>>(nullptr, 0, h0b[t & 1], h1b[(t - 1) & 1],
                                                        nullptr, nullptr, W1S, B1, h1b[t & 1], c1);
    }

    // 7) head (reads h1 of t=4 -> buffer index 0)
    head_mfma<<<Nn / 64, 256, 0, stream>>>(x, h1b[0], pwS, pb1, pw2, pb2, out);
}